// Round 15
// baseline (428.781 us; speedup 1.0000x reference)
//
#include <hip/hip_runtime.h>
#include <cstdint>

typedef unsigned short u16;
typedef uint32_t u32;
typedef __attribute__((ext_vector_type(8))) short bf16x8;
typedef __attribute__((ext_vector_type(4))) float f32x4;
typedef __attribute__((ext_vector_type(16))) float f32x16;

#define DIM_ 2048
#define S_   2048
#define B_   2
#define H_   16
#define HD_  128
#define M_   (B_ * S_)  // 4096

// ---------- scalar bf16 helpers (RNE) ----------
__device__ __forceinline__ u16 f2b(float f) {
  union { float f; uint32_t u; } v; v.f = f;
  uint32_t u = v.u;
  return (u16)((u + 0x7FFFu + ((u >> 16) & 1u)) >> 16);
}
__device__ __forceinline__ float b2f(u16 h) {
  union { uint32_t u; float f; } v; v.u = ((uint32_t)h) << 16;
  return v.f;
}

__device__ __forceinline__ u32 cvtpk(float lo, float hi) {
  u32 r;
  asm("v_cvt_pk_bf16_f32 %0, %1, %2" : "=v"(r) : "v"(lo), "v"(hi));
  return r;
}

// ---------- global -> LDS async copy (16B per lane, wave-uniform LDS base) ----------
typedef __attribute__((address_space(3))) u16 lds_u16_t;
typedef __attribute__((address_space(1))) const u16 glob_u16_t;

__device__ __forceinline__ void gload16(const u16* g, u16* l) {
  __builtin_amdgcn_global_load_lds((glob_u16_t*)g, (lds_u16_t*)l, 16, 0, 0);
}
#define GLD0(SRC, DST) \
  __builtin_amdgcn_global_load_lds((glob_u16_t*)(SRC), (lds_u16_t*)(DST), 16, 0, 0)

// ---------- fp32 -> bf16 convert (5 buffers) + RoPE table gen, one launch ----------
__global__ void convert6_kernel(const float* __restrict__ x, const float* __restrict__ wq,
                                const float* __restrict__ wk, const float* __restrict__ wv,
                                const float* __restrict__ wo, u16* __restrict__ xb,
                                u16* __restrict__ wqb, u16* __restrict__ wkb,
                                u16* __restrict__ wvb, u16* __restrict__ wob,
                                float* __restrict__ cosT, float* __restrict__ sinT) {
  if (blockIdx.y == 5) {
    // RoPE tables, TRANSPOSED [64 d][2048 s] fp32
    int idx = blockIdx.x * blockDim.x + threadIdx.x;
    if (idx >= 64 * S_) return;
    int d = idx >> 11;
    int s = idx & (S_ - 1);
    float inv = powf(10000.0f, -(float)d * (1.0f / 64.0f));
    float ang = (float)s * inv;
    cosT[idx] = cosf(ang);
    sinT[idx] = sinf(ang);
    return;
  }
  const float* src;
  u16* dst;
  int n;
  switch (blockIdx.y) {
    case 0: src = x;  dst = xb;  n = M_ * DIM_;   break;
    case 1: src = wq; dst = wqb; n = DIM_ * DIM_; break;
    case 2: src = wk; dst = wkb; n = DIM_ * DIM_; break;
    case 3: src = wv; dst = wvb; n = DIM_ * DIM_; break;
    default: src = wo; dst = wob; n = DIM_ * DIM_; break;
  }
  int i = (blockIdx.x * blockDim.x + threadIdx.x) * 4;
  const int stride = gridDim.x * blockDim.x * 4;
  for (; i < n; i += stride) {
    float4 v = *reinterpret_cast<const float4*>(src + i);
    uint64_t p = (uint64_t)f2b(v.x) | ((uint64_t)f2b(v.y) << 16) |
                 ((uint64_t)f2b(v.z) << 32) | ((uint64_t)f2b(v.w) << 48);
    *reinterpret_cast<uint64_t*>(dst + i) = p;
  }
}

// ==================================================================================
// GEMM v4 (QKV): m97-style single-buffered 2-barrier loop, LDS-traffic-minimized.
// BM=256 BN=128 BK=64; 256 thr = 4 waves (2M x 2N), wave tile 128x64 (acc 8x4).
// Reads/MFMA = 0.375 (was 0.5 at wave 64x64): 144KB LDS traffic per block-tile
// (96KB frag reads + 48KB DMA) for 4.2 MFLOP. 48KB LDS -> 3 blocks/CU; 768 blocks
// = exactly 3/CU, perfectly balanced, all co-resident (barrier drain hidden, m114).
// Chunk-XOR swizzle (slot = chunk ^ row&7), inverse-swizzled global src (rule 21).
// RoPE fused for z<2 (B-perm keeps (d,d+64) in-lane); z==2 writes V^T via split
// LDS bounce ([128 d][136 s], 2 s-half passes).
// ==================================================================================
#define NT_ 32  // 2048 / 64

__global__ __launch_bounds__(256, 3) void gemm_qkv4_kernel(
    const u16* __restrict__ xb, const u16* __restrict__ wqb, const u16* __restrict__ wkb,
    const u16* __restrict__ wvb, u16* __restrict__ qb, u16* __restrict__ kb,
    u16* __restrict__ vtb, const float* __restrict__ cosT, const float* __restrict__ sinT) {
  __shared__ __align__(16) u16 lds[24576];  // 48 KB: A [256][64] @0, B [128][64] @16384

  // XCD swizzle (768 % 8 == 0) + A-panel grouping: logical = mt*48 + z*16 + nt
  const int bid = blockIdx.x;
  const int logical = (bid & 7) * 96 + (bid >> 3);
  const int mt = logical / 48;
  const int rem = logical % 48;
  const int z = rem >> 4;
  const int nt = rem & 15;
  const u16* Wm = (z == 0) ? wqb : (z == 1) ? wkb : wvb;
  u16* out = (z == 0) ? qb : (z == 1) ? kb : vtb;

  const int tid = threadIdx.x;
  const int lane = tid & 63;
  const int w = tid >> 6;            // 0..3
  const int wm = w >> 1, wn = w & 1; // 2M x 2N, wave 128x64
  const int l15 = lane & 15, lg = lane >> 4;

  const u16* sA = xb + (size_t)(mt * 256) * DIM_;
  const u16* sB = Wm + (size_t)(nt * 128) * DIM_;

  // stage source voffset: row = tid>>3 (+32*sweep), chunk = (tid&7) ^ (row&7)
  const int r8 = tid >> 3;  // 0..31
  const int goffs = r8 * DIM_ + (((tid & 7) ^ (r8 & 7)) * 8);

  // LDS read bases (chunk ^= row&7; row%16 == l15 so row&7 == l15&7)
  const int x7 = l15 & 7;
  const int lrk0 = ((lg) ^ x7) * 8;
  const int lrk1 = ((4 | lg) ^ x7) * 8;
  const u16* pA0 = lds + (wm * 128 + l15) * 64 + lrk0;
  const u16* pA1 = lds + (wm * 128 + l15) * 64 + lrk1;
  const u16* pB0 = lds + 16384 + (wn * 32 + l15) * 64 + lrk0;
  const u16* pB1 = lds + 16384 + (wn * 32 + l15) * 64 + lrk1;

  f32x4 acc[8][4];
#pragma unroll
  for (int i = 0; i < 8; ++i)
#pragma unroll
    for (int j = 0; j < 4; ++j) acc[i][j] = (f32x4){0.f, 0.f, 0.f, 0.f};

  bf16x8 a[8], b[4];

  for (int t = 0; t < NT_; ++t) {
    __syncthreads();  // previous tile's frag reads complete before overwrite
#pragma unroll
    for (int s = 0; s < 8; ++s)
      GLD0(sA + goffs + s * (32 * DIM_), lds + s * 2048 + w * 512);
#pragma unroll
    for (int s = 0; s < 4; ++s)
      GLD0(sB + goffs + s * (32 * DIM_), lds + 16384 + s * 2048 + w * 512);
    sA += 64; sB += 64;
    __syncthreads();  // vmcnt(0) drain -> tile ready (hidden by co-resident blocks)

    // ks0: B-perm cols (ni&1)*16 + (ni>>1)*64 within head
#pragma unroll
    for (int mi = 0; mi < 8; ++mi) a[mi] = *(const bf16x8*)(pA0 + mi * 1024);
#pragma unroll
    for (int ni = 0; ni < 4; ++ni)
      b[ni] = *(const bf16x8*)(pB0 + (ni & 1) * 1024 + (ni >> 1) * 4096);
    __builtin_amdgcn_s_setprio(1);
#pragma unroll
    for (int mi = 0; mi < 8; ++mi)
#pragma unroll
      for (int ni = 0; ni < 4; ++ni)
        acc[mi][ni] = __builtin_amdgcn_mfma_f32_16x16x32_bf16(a[mi], b[ni], acc[mi][ni], 0, 0, 0);
    __builtin_amdgcn_s_setprio(0);
    // ks1
#pragma unroll
    for (int mi = 0; mi < 8; ++mi) a[mi] = *(const bf16x8*)(pA1 + mi * 1024);
#pragma unroll
    for (int ni = 0; ni < 4; ++ni)
      b[ni] = *(const bf16x8*)(pB1 + (ni & 1) * 1024 + (ni >> 1) * 4096);
    __builtin_amdgcn_s_setprio(1);
#pragma unroll
    for (int mi = 0; mi < 8; ++mi)
#pragma unroll
      for (int ni = 0; ni < 4; ++ni)
        acc[mi][ni] = __builtin_amdgcn_mfma_f32_16x16x32_bf16(a[mi], b[ni], acc[mi][ni], 0, 0, 0);
    __builtin_amdgcn_s_setprio(0);
  }

  if (z < 2) {
    // ---- fused RoPE epilogue: pair (d, d+64) = acc[mi][ni] / acc[mi][ni+2] ----
#pragma unroll
    for (int mi = 0; mi < 8; ++mi) {
      const int row = mt * 256 + wm * 128 + mi * 16 + lg * 4;
      const int s = row & (S_ - 1);
#pragma unroll
      for (int ni = 0; ni < 2; ++ni) {
        const int d = wn * 32 + ni * 16 + l15;  // < 64
        const float4 c4 = *(const float4*)(cosT + d * S_ + s);
        const float4 s4 = *(const float4*)(sinT + d * S_ + s);
        const float cc[4]  = {c4.x, c4.y, c4.z, c4.w};
        const float ssn[4] = {s4.x, s4.y, s4.z, s4.w};
        u16* p = out + (size_t)row * DIM_ + nt * 128 + d;
#pragma unroll
        for (int r = 0; r < 4; ++r) {
          const float t1 = acc[mi][ni][r];
          const float t2 = acc[mi][ni + 2][r];
          p[(size_t)r * DIM_]      = f2b(t1 * cc[r] - t2 * ssn[r]);
          p[(size_t)r * DIM_ + 64] = f2b(t2 * cc[r] + t1 * ssn[r]);
        }
      }
    }
  } else {
    // ---- V^T epilogue: split LDS bounce [128 d][136 s] x 2 passes (s-halves) ----
    const int bq = mt >> 3;
    const int sbase = (mt * 256) & (S_ - 1);
#pragma unroll
    for (int shalf = 0; shalf < 2; ++shalf) {
      __syncthreads();  // K-loop reads / previous pass streams complete
      if (wm == shalf) {
#pragma unroll
        for (int mi = 0; mi < 8; ++mi) {
          const int sl = mi * 16 + lg * 4;  // 0..127 within this s-half
#pragma unroll
          for (int ni = 0; ni < 4; ++ni) {
            const int d = wn * 32 + (ni & 1) * 16 + (ni >> 1) * 64 + l15;  // 0..127
            const u32 lo  = cvtpk(acc[mi][ni][0], acc[mi][ni][1]);
            const u32 hi2 = cvtpk(acc[mi][ni][2], acc[mi][ni][3]);
            const uint64_t pk = (uint64_t)lo | ((uint64_t)hi2 << 32);
            *(uint64_t*)(lds + d * 136 + sl) = pk;
          }
        }
      }
      __syncthreads();
      // stream: 16 lanes per d-row (128 s = 16 x bf16x8), 16 d per iter, 8 iters
#pragma unroll
      for (int it = 0; it < 8; ++it) {
        const int d = it * 16 + (tid >> 4);  // 0..127
        const bf16x8 val = *(const bf16x8*)(lds + d * 136 + (tid & 15) * 8);
        *(bf16x8*)(out + ((size_t)(bq * 16 + nt) * 128 + d) * S_ + sbase + shalf * 128 +
                   (tid & 15) * 8) = val;
      }
    }
  }
}

// ---------------- O-projection: BM=128 BN=128, 256 thr / 4 waves, 32 KB LDS ----------------
__global__ __launch_bounds__(256, 4) void gemm_out3_kernel(const u16* __restrict__ A,
                                                           const u16* __restrict__ W,
                                                           float* __restrict__ Cf) {
  __shared__ __align__(16) u16 lds[16384];  // 32 KB: A [128][64] @0, B [128][64] @8192
  const int bid = blockIdx.x;  // 512 blocks, all resident
  const int logical = (bid & 7) * 64 + (bid >> 3);
  const int mt = logical >> 4;  // 0..31
  const int nt = logical & 15;

  const int tid = threadIdx.x;
  const int lane = tid & 63;
  const int w = tid >> 6;
  const int wm = w >> 1, wn = w & 1;
  const int l15 = lane & 15, lg = lane >> 4;

  const u16* sA = A + (size_t)(mt * 128) * DIM_;
  const u16* sB = W + (size_t)(nt * 128) * DIM_;

  const int r8 = tid >> 3;  // 0..31
  const int goffs = r8 * DIM_ + (((tid & 7) ^ (r8 & 7)) * 8);

  const int x7 = l15 & 7;
  const int lrk0 = ((lg) ^ x7) * 8;
  const int lrk1 = ((4 | lg) ^ x7) * 8;
  const u16* pA0 = lds + (wm * 64 + l15) * 64 + lrk0;
  const u16* pA1 = lds + (wm * 64 + l15) * 64 + lrk1;
  const u16* pB0 = lds + 8192 + (wn * 64 + l15) * 64 + lrk0;
  const u16* pB1 = lds + 8192 + (wn * 64 + l15) * 64 + lrk1;

  f32x4 acc[4][4];
#pragma unroll
  for (int i = 0; i < 4; ++i)
#pragma unroll
    for (int j = 0; j < 4; ++j) acc[i][j] = (f32x4){0.f, 0.f, 0.f, 0.f};

  bf16x8 a[4], b[4];

  for (int t = 0; t < NT_; ++t) {
    __syncthreads();
#pragma unroll
    for (int s = 0; s < 4; ++s)
      GLD0(sA + goffs + s * (32 * DIM_), lds + s * 2048 + w * 512);
#pragma unroll
    for (int s = 0; s < 4; ++s)
      GLD0(sB + goffs + s * (32 * DIM_), lds + 8192 + s * 2048 + w * 512);
    sA += 64; sB += 64;
    __syncthreads();

#pragma unroll
    for (int mi = 0; mi < 4; ++mi) a[mi] = *(const bf16x8*)(pA0 + mi * 1024);
#pragma unroll
    for (int ni = 0; ni < 4; ++ni) b[ni] = *(const bf16x8*)(pB0 + ni * 1024);
    __builtin_amdgcn_s_setprio(1);
#pragma unroll
    for (int mi = 0; mi < 4; ++mi)
#pragma unroll
      for (int ni = 0; ni < 4; ++ni)
        acc[mi][ni] = __builtin_amdgcn_mfma_f32_16x16x32_bf16(a[mi], b[ni], acc[mi][ni], 0, 0, 0);
    __builtin_amdgcn_s_setprio(0);
#pragma unroll
    for (int mi = 0; mi < 4; ++mi) a[mi] = *(const bf16x8*)(pA1 + mi * 1024);
#pragma unroll
    for (int ni = 0; ni < 4; ++ni) b[ni] = *(const bf16x8*)(pB1 + ni * 1024);
    __builtin_amdgcn_s_setprio(1);
#pragma unroll
    for (int mi = 0; mi < 4; ++mi)
#pragma unroll
      for (int ni = 0; ni < 4; ++ni)
        acc[mi][ni] = __builtin_amdgcn_mfma_f32_16x16x32_bf16(a[mi], b[ni], acc[mi][ni], 0, 0, 0);
    __builtin_amdgcn_s_setprio(0);
  }

#pragma unroll
  for (int mi = 0; mi < 4; ++mi)
#pragma unroll
    for (int ni = 0; ni < 4; ++ni) {
      const int row = mt * 128 + wm * 64 + mi * 16 + lg * 4;
      const int col = nt * 128 + wn * 64 + ni * 16 + l15;
#pragma unroll
      for (int r = 0; r < 4; ++r)
        Cf[(size_t)(row + r) * DIM_ + col] = acc[mi][ni][r];
    }
}

// ==================================================================================
// Causal flash attention (unchanged): dbuf K and V, both staged by pure DMA
// (V from V^T buffer). One __syncthreads() per tile. Complementary-qt pairing.
// ==================================================================================
#define CEXP 0.12751744f  /* (1/sqrt(128)) * log2(e) */

__global__ __launch_bounds__(256, 2) void attn_kernel(const u16* __restrict__ q,
                                                      const u16* __restrict__ k,
                                                      const u16* __restrict__ vt,
                                                      u16* __restrict__ ao) {
  __shared__ __align__(16) u16 smem[32768];  // 64 KB
  u16* kTl = smem;
  u16* vTl = smem + 16384;

  const int qt   = blockIdx.z ? (int)blockIdx.x : (int)(gridDim.x - 1 - blockIdx.x);
  const int head = blockIdx.y;
  const int b    = blockIdx.z;
  const int t = threadIdx.x;
  const int lane = t & 63;
  const int w = t >> 6;
  const int l31 = lane & 31;
  const int hi = lane >> 5;
  const int kxor = (lane & 7) << 3;
  const int qrow0 = qt * 128 + w * 32;
  const size_t bS = (size_t)b * S_;
  const size_t vhead = (size_t)(b * 16 + head) * 128 * S_;

  bf16x8 qf[8];
  {
    const u16* qrow = q + (bS + qrow0 + l31) * DIM_ + head * HD_;
#pragma unroll
    for (int st = 0; st < 8; ++st)
      qf[st] = *(const bf16x8*)(qrow + st * 16 + hi * 8);
  }

  f32x16 accO[4];
#pragma unroll
  for (int db = 0; db < 4; ++db)
#pragma unroll
    for (int rr = 0; rr < 16; ++rr) accO[db][rr] = 0.f;
  float m = -1e30f, l = 0.f;

  const int tmax_w = 2 * qt + (w >> 1);
  const int ttend = 2 * qt + 1;

  auto stageK = [&](int buf, int tt) {
#pragma unroll
    for (int p = 0; p < 4; ++p) {
      const int cid = p * 256 + w * 64 + lane;
      const int kr = cid >> 4;
      const int cg = (cid & 15) ^ (kr & 7);
      gload16(k + (bS + tt * 64 + kr) * DIM_ + head * HD_ + cg * 8,
              kTl + buf * 8192 + (p * 256 + w * 64) * 8);
    }
  };
  auto stageV = [&](int buf, int tt) {
#pragma unroll
    for (int p = 0; p < 4; ++p) {
      const int cid = p * 256 + w * 64 + lane;
      const int d = cid >> 3;
      const int cg = (cid & 7) ^ (d & 7);
      gload16(vt + vhead + (size_t)d * S_ + tt * 64 + cg * 8,
              vTl + buf * 8192 + (p * 256 + w * 64) * 8);
    }
  };

  stageK(0, 0);
  stageV(0, 0);
  __syncthreads();

  for (int tt = 0; tt <= ttend; ++tt) {
    const int cur = tt & 1;
    const int alt = cur ^ 1;

    if (tt + 1 <= ttend) {
      stageK(alt, tt + 1);
      stageV(alt, tt + 1);
    }

    if (tt <= tmax_w) {
      const u16* kB = kTl + cur * 8192;
      const u16* vB = vTl + cur * 8192;
      f32x16 sA, sB;
#pragma unroll
      for (int rr = 0; rr < 16; ++rr) { sA[rr] = 0.f; sB[rr] = 0.f; }
      __builtin_amdgcn_s_setprio(1);
#pragma unroll
      for (int st = 0; st < 8; ++st) {
        const int dc = st * 16 + hi * 8;
        bf16x8 k0 = *(const bf16x8*)(kB + l31 * 128 + (dc ^ kxor));
        bf16x8 k1 = *(const bf16x8*)(kB + (32 + l31) * 128 + (dc ^ kxor));
        sA = __builtin_amdgcn_mfma_f32_32x32x16_bf16(k0, qf[st], sA, 0, 0, 0);
        sB = __builtin_amdgcn_mfma_f32_32x32x16_bf16(k1, qf[st], sB, 0, 0, 0);
      }
      __builtin_amdgcn_s_setprio(0);

      const int qg = qrow0 + l31;
      if (tt * 64 + 63 > qrow0) {
        const int kb = tt * 64 + 4 * hi;
#pragma unroll
        for (int rr = 0; rr < 16; ++rr) {
          const int kg = kb + (rr & 3) + 8 * (rr >> 2);
          sA[rr] = (kg <= qg) ? sA[rr] : -1e30f;
          sB[rr] = (kg + 32 <= qg) ? sB[rr] : -1e30f;
        }
      }

      float mx[8];
#pragma unroll
      for (int i = 0; i < 8; ++i)
        mx[i] = fmaxf(fmaxf(sA[i], sA[i + 8]), fmaxf(sB[i], sB[i + 8]));
#pragma unroll
      for (int i = 0; i < 4; ++i) mx[i] = fmaxf(mx[i], mx[i + 4]);
      float pm = fmaxf(fmaxf(mx[0], mx[1]), fmaxf(mx[2], mx[3]));
      pm = fmaxf(pm, __shfl_xor(pm, 32));
      const float mN = fmaxf(m, pm);
      if (!__all(pm - m <= 90.5f)) {  // T13 defer-max
        const float osc = exp2f((m - mN) * CEXP);
        l *= osc;
#pragma unroll
        for (int db = 0; db < 4; ++db)
#pragma unroll
          for (int rr = 0; rr < 16; ++rr) accO[db][rr] *= osc;
        m = mN;
      }
      const float mc = m * CEXP;
      float lsv[4] = {0.f, 0.f, 0.f, 0.f};
#pragma unroll
      for (int rr = 0; rr < 16; ++rr) {
        const float pa = exp2f(__builtin_fmaf(sA[rr], CEXP, -mc));
        const float pb = exp2f(__builtin_fmaf(sB[rr], CEXP, -mc));
        sA[rr] = pa; sB[rr] = pb;
        lsv[rr & 3] += pa + pb;
      }
      float ls = (lsv[0] + lsv[1]) + (lsv[2] + lsv[3]);
      ls += __shfl_xor(ls, 32);
      l += ls;

#define PV_STEP(ARR, R0, ST2)                                                      \
      {                                                                            \
        u32 a0 = cvtpk(ARR[(R0) + 0], ARR[(R0) + 1]);                              \
        u32 a1 = cvtpk(ARR[(R0) + 2], ARR[(R0) + 3]);                              \
        u32 b0 = cvtpk(ARR[(R0) + 4], ARR[(R0) + 5]);                              \
        u32 b1 = cvtpk(ARR[(R0) + 6], ARR[(R0) + 7]);                              \
        asm("v_permlane32_swap_b32 %0, %1" : "+v"(a0), "+v"(b0));                  \
        asm("v_permlane32_swap_b32 %0, %1" : "+v"(a1), "+v"(b1));                  \
        union { u32 uu[4]; bf16x8 v8; } pf;                                        \
        pf.uu[0] = a0; pf.uu[1] = a1; pf.uu[2] = b0; pf.uu[3] = b1;                \
        const int ko = (ST2) * 16 + hi * 8;                                        \
        __builtin_amdgcn_s_setprio(1);                                             \
        _Pragma("unroll")                                                          \
        for (int db = 0; db < 4; ++db) {                                           \
          const int dr = db * 32 + l31;                                            \
          bf16x8 vf = *(const bf16x8*)(vB + dr * 64 + (ko ^ kxor));                \
          accO[db] =                                                               \
              __builtin_amdgcn_mfma_f32_32x32x16_bf16(vf, pf.v8, accO[db], 0, 0, 0); \
        }                                                                          \
        __builtin_amdgcn_s_setprio(0);                                             \
      }
      PV_STEP(sA, 0, 0)
      PV_STEP(sA, 8, 1)
      PV_STEP(sB, 0, 2)
      PV_STEP(sB, 8, 3)
#undef PV_STEP
    }

    __syncthreads();  // vmcnt(0)+lgkmcnt(0)+barrier: K/V DMA for t+1 landed
  }

  // ---- epilogue: normalize, transpose O^T->O through LDS, coalesced store ----
  const float linv = 1.0f / l;
  u16* oT = smem + w * 4352;
#pragma unroll
  for (int db = 0; db < 4; ++db)
#pragma unroll
    for (int q4 = 0; q4 < 4; ++q4) {
      const int dbase = db * 32 + q4 * 8 + hi * 4;
      const u32 lo = cvtpk(accO[db][q4 * 4 + 0] * linv, accO[db][q4 * 4 + 1] * linv);
      const u32 hiw = cvtpk(accO[db][q4 * 4 + 2] * linv, accO[db][q4 * 4 + 3] * linv);
      *(u32*)(oT + l31 * 136 + dbase) = lo;
      *(u32*)(oT + l31 * 136 + dbase + 2) = hiw;
    }
  __syncthreads();
#pragma unroll
  for (int i = 0; i < 8; ++i) {
    const int cid = i * 64 + lane;
    const int qloc = cid >> 4;
    const int c = cid & 15;
    const bf16x8 val = *(const bf16x8*)(oT + qloc * 136 + c * 8);
    *(bf16x8*)(ao + (bS + qrow0 + qloc) * DIM_ + head * HD_ + c * 8) = val;
  }
}

// ---------- launch ----------
extern "C" void kernel_launch(void* const* d_in, const int* in_sizes, int n_in,
                              void* d_out, int out_size, void* d_ws, size_t ws_size,
                              hipStream_t stream) {
  const float* x  = (const float*)d_in[0];
  const float* wq = (const float*)d_in[2];
  const float* wk = (const float*)d_in[3];
  const float* wv = (const float*)d_in[4];
  const float* wo = (const float*)d_in[5];

  char* ws = (char*)d_ws;
  size_t off = 0;
  auto carve = [&](size_t bytes) { char* p = ws + off; off += bytes; return p; };
  u16* xb   = (u16*)carve((size_t)M_ * DIM_ * 2);
  u16* wqb  = (u16*)carve((size_t)DIM_ * DIM_ * 2);
  u16* wkb  = (u16*)carve((size_t)DIM_ * DIM_ * 2);
  u16* wvb  = (u16*)carve((size_t)DIM_ * DIM_ * 2);
  u16* wob  = (u16*)carve((size_t)DIM_ * DIM_ * 2);
  u16* qb   = (u16*)carve((size_t)M_ * DIM_ * 2);
  u16* kb   = (u16*)carve((size_t)M_ * DIM_ * 2);
  u16* vtb  = (u16*)carve((size_t)M_ * DIM_ * 2);  // V^T [b][h][d][s]
  u16* aob  = (u16*)carve((size_t)M_ * DIM_ * 2);
  float* cosT = (float*)carve((size_t)64 * S_ * 4);
  float* sinT = (float*)carve((size_t)64 * S_ * 4);
  if (off > ws_size) return;

  dim3 gc(1024, 6);
  convert6_kernel<<<gc, 256, 0, stream>>>(x, wq, wk, wv, wo, xb, wqb, wkb, wvb, wob,
                                          cosT, sinT);

  gemm_qkv4_kernel<<<768, 256, 0, stream>>>(xb, wqb, wkb, wvb, qb, kb, vtb, cosT, sinT);

  dim3 ga(16, H_, B_);
  attn_kernel<<<ga, 256, 0, stream>>>(qb, kb, vtb, aob);

  gemm_out3_kernel<<<512, 256, 0, stream>>>(aob, wob, (float*)d_out);
}

// Round 16
// 243.959 us; speedup vs baseline: 1.7576x; 1.7576x over previous
//
#include <hip/hip_runtime.h>
#include <cstdint>

typedef unsigned short u16;
typedef uint32_t u32;
typedef __attribute__((ext_vector_type(8))) short bf16x8;
typedef __attribute__((ext_vector_type(4))) float f32x4;
typedef __attribute__((ext_vector_type(16))) float f32x16;

#define DIM_ 2048
#define S_   2048
#define B_   2
#define H_   16
#define HD_  128
#define M_   (B_ * S_)  // 4096

// ---------- scalar bf16 helpers (RNE) ----------
__device__ __forceinline__ u16 f2b(float f) {
  union { float f; uint32_t u; } v; v.f = f;
  uint32_t u = v.u;
  return (u16)((u + 0x7FFFu + ((u >> 16) & 1u)) >> 16);
}
__device__ __forceinline__ float b2f(u16 h) {
  union { uint32_t u; float f; } v; v.u = ((uint32_t)h) << 16;
  return v.f;
}

__device__ __forceinline__ u32 cvtpk(float lo, float hi) {
  u32 r;
  asm("v_cvt_pk_bf16_f32 %0, %1, %2" : "=v"(r) : "v"(lo), "v"(hi));
  return r;
}

// ---------- global -> LDS async copy (16B per lane, wave-uniform LDS base) ----------
typedef __attribute__((address_space(3))) u16 lds_u16_t;
typedef __attribute__((address_space(1))) const u16 glob_u16_t;

__device__ __forceinline__ void gload16(const u16* g, u16* l) {
  __builtin_amdgcn_global_load_lds((glob_u16_t*)g, (lds_u16_t*)l, 16, 0, 0);
}
#define GLD0(SRC, DST) \
  __builtin_amdgcn_global_load_lds((glob_u16_t*)(SRC), (lds_u16_t*)(DST), 16, 0, 0)

// ---------- fp32 -> bf16 convert (5 buffers) + RoPE table gen, one launch ----------
__global__ void convert6_kernel(const float* __restrict__ x, const float* __restrict__ wq,
                                const float* __restrict__ wk, const float* __restrict__ wv,
                                const float* __restrict__ wo, u16* __restrict__ xb,
                                u16* __restrict__ wqb, u16* __restrict__ wkb,
                                u16* __restrict__ wvb, u16* __restrict__ wob,
                                float* __restrict__ cosT, float* __restrict__ sinT) {
  if (blockIdx.y == 5) {
    // RoPE tables, TRANSPOSED [64 d][2048 s] fp32
    int idx = blockIdx.x * blockDim.x + threadIdx.x;
    if (idx >= 64 * S_) return;
    int d = idx >> 11;
    int s = idx & (S_ - 1);
    float inv = powf(10000.0f, -(float)d * (1.0f / 64.0f));
    float ang = (float)s * inv;
    cosT[idx] = cosf(ang);
    sinT[idx] = sinf(ang);
    return;
  }
  const float* src;
  u16* dst;
  int n;
  switch (blockIdx.y) {
    case 0: src = x;  dst = xb;  n = M_ * DIM_;   break;
    case 1: src = wq; dst = wqb; n = DIM_ * DIM_; break;
    case 2: src = wk; dst = wkb; n = DIM_ * DIM_; break;
    case 3: src = wv; dst = wvb; n = DIM_ * DIM_; break;
    default: src = wo; dst = wob; n = DIM_ * DIM_; break;
  }
  int i = (blockIdx.x * blockDim.x + threadIdx.x) * 4;
  const int stride = gridDim.x * blockDim.x * 4;
  for (; i < n; i += stride) {
    float4 v = *reinterpret_cast<const float4*>(src + i);
    uint64_t p = (uint64_t)f2b(v.x) | ((uint64_t)f2b(v.y) << 16) |
                 ((uint64_t)f2b(v.z) << 32) | ((uint64_t)f2b(v.w) << 48);
    *reinterpret_cast<uint64_t*>(dst + i) = p;
  }
}

// ==================================================================================
// GEMM v4 (QKV): m97-style single-buffered 2-barrier loop, LDS-traffic-minimized.
// BM=256 BN=128 BK=64; 256 thr = 4 waves (2M x 2N), wave tile 128x64 (acc 8x4).
// __launch_bounds__(256, 2): unified VGPR+AGPR cap 256/wave -- the kernel needs
// ~200, so NO SPILL (R15's (256,3) capped at ~170 -> acc spilled to scratch,
// 855 MB writes, 3.6x regression). 2 blocks/CU co-resident hides barrier drain.
// LDS traffic/CU-tile = 2 x (96KB reads + 48KB DMA) = 288 KB vs R14's 528 KB.
// Chunk-XOR swizzle (slot = chunk ^ row&7), inverse-swizzled global src (rule 21).
// RoPE fused for z<2 (B-perm keeps (d,d+64) in-lane); z==2 writes V^T via split
// LDS bounce ([128 d][136 s], 2 s-half passes).
// ==================================================================================
#define NT_ 32  // 2048 / 64

__global__ __launch_bounds__(256, 2) void gemm_qkv4_kernel(
    const u16* __restrict__ xb, const u16* __restrict__ wqb, const u16* __restrict__ wkb,
    const u16* __restrict__ wvb, u16* __restrict__ qb, u16* __restrict__ kb,
    u16* __restrict__ vtb, const float* __restrict__ cosT, const float* __restrict__ sinT) {
  __shared__ __align__(16) u16 lds[24576];  // 48 KB: A [256][64] @0, B [128][64] @16384

  // XCD swizzle (768 % 8 == 0) + A-panel grouping: logical = mt*48 + z*16 + nt
  const int bid = blockIdx.x;
  const int logical = (bid & 7) * 96 + (bid >> 3);
  const int mt = logical / 48;
  const int rem = logical % 48;
  const int z = rem >> 4;
  const int nt = rem & 15;
  const u16* Wm = (z == 0) ? wqb : (z == 1) ? wkb : wvb;
  u16* out = (z == 0) ? qb : (z == 1) ? kb : vtb;

  const int tid = threadIdx.x;
  const int lane = tid & 63;
  const int w = tid >> 6;            // 0..3
  const int wm = w >> 1, wn = w & 1; // 2M x 2N, wave 128x64
  const int l15 = lane & 15, lg = lane >> 4;

  const u16* sA = xb + (size_t)(mt * 256) * DIM_;
  const u16* sB = Wm + (size_t)(nt * 128) * DIM_;

  // stage source voffset: row = tid>>3 (+32*sweep), chunk = (tid&7) ^ (row&7)
  const int r8 = tid >> 3;  // 0..31
  const int goffs = r8 * DIM_ + (((tid & 7) ^ (r8 & 7)) * 8);

  // LDS read bases (chunk ^= row&7; row%16 == l15 so row&7 == l15&7)
  const int x7 = l15 & 7;
  const int lrk0 = ((lg) ^ x7) * 8;
  const int lrk1 = ((4 | lg) ^ x7) * 8;
  const u16* pA0 = lds + (wm * 128 + l15) * 64 + lrk0;
  const u16* pA1 = lds + (wm * 128 + l15) * 64 + lrk1;
  const u16* pB0 = lds + 16384 + (wn * 32 + l15) * 64 + lrk0;
  const u16* pB1 = lds + 16384 + (wn * 32 + l15) * 64 + lrk1;

  f32x4 acc[8][4];
#pragma unroll
  for (int i = 0; i < 8; ++i)
#pragma unroll
    for (int j = 0; j < 4; ++j) acc[i][j] = (f32x4){0.f, 0.f, 0.f, 0.f};

  bf16x8 a[8], b[4];

  for (int t = 0; t < NT_; ++t) {
    __syncthreads();  // previous tile's frag reads complete before overwrite
#pragma unroll
    for (int s = 0; s < 8; ++s)
      GLD0(sA + goffs + s * (32 * DIM_), lds + s * 2048 + w * 512);
#pragma unroll
    for (int s = 0; s < 4; ++s)
      GLD0(sB + goffs + s * (32 * DIM_), lds + 16384 + s * 2048 + w * 512);
    sA += 64; sB += 64;
    __syncthreads();  // vmcnt(0) drain -> tile ready (hidden by co-resident block)

    // ks0: B-perm cols (ni&1)*16 + (ni>>1)*64 within head
#pragma unroll
    for (int mi = 0; mi < 8; ++mi) a[mi] = *(const bf16x8*)(pA0 + mi * 1024);
#pragma unroll
    for (int ni = 0; ni < 4; ++ni)
      b[ni] = *(const bf16x8*)(pB0 + (ni & 1) * 1024 + (ni >> 1) * 4096);
    __builtin_amdgcn_s_setprio(1);
#pragma unroll
    for (int mi = 0; mi < 8; ++mi)
#pragma unroll
      for (int ni = 0; ni < 4; ++ni)
        acc[mi][ni] = __builtin_amdgcn_mfma_f32_16x16x32_bf16(a[mi], b[ni], acc[mi][ni], 0, 0, 0);
    __builtin_amdgcn_s_setprio(0);
    // ks1
#pragma unroll
    for (int mi = 0; mi < 8; ++mi) a[mi] = *(const bf16x8*)(pA1 + mi * 1024);
#pragma unroll
    for (int ni = 0; ni < 4; ++ni)
      b[ni] = *(const bf16x8*)(pB1 + (ni & 1) * 1024 + (ni >> 1) * 4096);
    __builtin_amdgcn_s_setprio(1);
#pragma unroll
    for (int mi = 0; mi < 8; ++mi)
#pragma unroll
      for (int ni = 0; ni < 4; ++ni)
        acc[mi][ni] = __builtin_amdgcn_mfma_f32_16x16x32_bf16(a[mi], b[ni], acc[mi][ni], 0, 0, 0);
    __builtin_amdgcn_s_setprio(0);
  }

  if (z < 2) {
    // ---- fused RoPE epilogue: pair (d, d+64) = acc[mi][ni] / acc[mi][ni+2] ----
#pragma unroll
    for (int mi = 0; mi < 8; ++mi) {
      const int row = mt * 256 + wm * 128 + mi * 16 + lg * 4;
      const int s = row & (S_ - 1);
#pragma unroll
      for (int ni = 0; ni < 2; ++ni) {
        const int d = wn * 32 + ni * 16 + l15;  // < 64
        const float4 c4 = *(const float4*)(cosT + d * S_ + s);
        const float4 s4 = *(const float4*)(sinT + d * S_ + s);
        const float cc[4]  = {c4.x, c4.y, c4.z, c4.w};
        const float ssn[4] = {s4.x, s4.y, s4.z, s4.w};
        u16* p = out + (size_t)row * DIM_ + nt * 128 + d;
#pragma unroll
        for (int r = 0; r < 4; ++r) {
          const float t1 = acc[mi][ni][r];
          const float t2 = acc[mi][ni + 2][r];
          p[(size_t)r * DIM_]      = f2b(t1 * cc[r] - t2 * ssn[r]);
          p[(size_t)r * DIM_ + 64] = f2b(t2 * cc[r] + t1 * ssn[r]);
        }
      }
    }
  } else {
    // ---- V^T epilogue: split LDS bounce [128 d][136 s] x 2 passes (s-halves) ----
    const int bq = mt >> 3;
    const int sbase = (mt * 256) & (S_ - 1);
#pragma unroll
    for (int shalf = 0; shalf < 2; ++shalf) {
      __syncthreads();  // K-loop reads / previous pass streams complete
      if (wm == shalf) {
#pragma unroll
        for (int mi = 0; mi < 8; ++mi) {
          const int sl = mi * 16 + lg * 4;  // 0..127 within this s-half
#pragma unroll
          for (int ni = 0; ni < 4; ++ni) {
            const int d = wn * 32 + (ni & 1) * 16 + (ni >> 1) * 64 + l15;  // 0..127
            const u32 lo  = cvtpk(acc[mi][ni][0], acc[mi][ni][1]);
            const u32 hi2 = cvtpk(acc[mi][ni][2], acc[mi][ni][3]);
            const uint64_t pk = (uint64_t)lo | ((uint64_t)hi2 << 32);
            *(uint64_t*)(lds + d * 136 + sl) = pk;
          }
        }
      }
      __syncthreads();
      // stream: 16 lanes per d-row (128 s = 16 x bf16x8), 16 d per iter, 8 iters
#pragma unroll
      for (int it = 0; it < 8; ++it) {
        const int d = it * 16 + (tid >> 4);  // 0..127
        const bf16x8 val = *(const bf16x8*)(lds + d * 136 + (tid & 15) * 8);
        *(bf16x8*)(out + ((size_t)(bq * 16 + nt) * 128 + d) * S_ + sbase + shalf * 128 +
                   (tid & 15) * 8) = val;
      }
    }
  }
}

// ---------------- O-projection: BM=128 BN=128, 256 thr / 4 waves, 32 KB LDS ----------------
__global__ __launch_bounds__(256, 4) void gemm_out3_kernel(const u16* __restrict__ A,
                                                           const u16* __restrict__ W,
                                                           float* __restrict__ Cf) {
  __shared__ __align__(16) u16 lds[16384];  // 32 KB: A [128][64] @0, B [128][64] @8192
  const int bid = blockIdx.x;  // 512 blocks, all resident
  const int logical = (bid & 7) * 64 + (bid >> 3);
  const int mt = logical >> 4;  // 0..31
  const int nt = logical & 15;

  const int tid = threadIdx.x;
  const int lane = tid & 63;
  const int w = tid >> 6;
  const int wm = w >> 1, wn = w & 1;
  const int l15 = lane & 15, lg = lane >> 4;

  const u16* sA = A + (size_t)(mt * 128) * DIM_;
  const u16* sB = W + (size_t)(nt * 128) * DIM_;

  const int r8 = tid >> 3;  // 0..31
  const int goffs = r8 * DIM_ + (((tid & 7) ^ (r8 & 7)) * 8);

  const int x7 = l15 & 7;
  const int lrk0 = ((lg) ^ x7) * 8;
  const int lrk1 = ((4 | lg) ^ x7) * 8;
  const u16* pA0 = lds + (wm * 64 + l15) * 64 + lrk0;
  const u16* pA1 = lds + (wm * 64 + l15) * 64 + lrk1;
  const u16* pB0 = lds + 8192 + (wn * 64 + l15) * 64 + lrk0;
  const u16* pB1 = lds + 8192 + (wn * 64 + l15) * 64 + lrk1;

  f32x4 acc[4][4];
#pragma unroll
  for (int i = 0; i < 4; ++i)
#pragma unroll
    for (int j = 0; j < 4; ++j) acc[i][j] = (f32x4){0.f, 0.f, 0.f, 0.f};

  bf16x8 a[4], b[4];

  for (int t = 0; t < NT_; ++t) {
    __syncthreads();
#pragma unroll
    for (int s = 0; s < 4; ++s)
      GLD0(sA + goffs + s * (32 * DIM_), lds + s * 2048 + w * 512);
#pragma unroll
    for (int s = 0; s < 4; ++s)
      GLD0(sB + goffs + s * (32 * DIM_), lds + 8192 + s * 2048 + w * 512);
    sA += 64; sB += 64;
    __syncthreads();

#pragma unroll
    for (int mi = 0; mi < 4; ++mi) a[mi] = *(const bf16x8*)(pA0 + mi * 1024);
#pragma unroll
    for (int ni = 0; ni < 4; ++ni) b[ni] = *(const bf16x8*)(pB0 + ni * 1024);
    __builtin_amdgcn_s_setprio(1);
#pragma unroll
    for (int mi = 0; mi < 4; ++mi)
#pragma unroll
      for (int ni = 0; ni < 4; ++ni)
        acc[mi][ni] = __builtin_amdgcn_mfma_f32_16x16x32_bf16(a[mi], b[ni], acc[mi][ni], 0, 0, 0);
    __builtin_amdgcn_s_setprio(0);
#pragma unroll
    for (int mi = 0; mi < 4; ++mi) a[mi] = *(const bf16x8*)(pA1 + mi * 1024);
#pragma unroll
    for (int ni = 0; ni < 4; ++ni) b[ni] = *(const bf16x8*)(pB1 + ni * 1024);
    __builtin_amdgcn_s_setprio(1);
#pragma unroll
    for (int mi = 0; mi < 4; ++mi)
#pragma unroll
      for (int ni = 0; ni < 4; ++ni)
        acc[mi][ni] = __builtin_amdgcn_mfma_f32_16x16x32_bf16(a[mi], b[ni], acc[mi][ni], 0, 0, 0);
    __builtin_amdgcn_s_setprio(0);
  }

#pragma unroll
  for (int mi = 0; mi < 4; ++mi)
#pragma unroll
    for (int ni = 0; ni < 4; ++ni) {
      const int row = mt * 128 + wm * 64 + mi * 16 + lg * 4;
      const int col = nt * 128 + wn * 64 + ni * 16 + l15;
#pragma unroll
      for (int r = 0; r < 4; ++r)
        Cf[(size_t)(row + r) * DIM_ + col] = acc[mi][ni][r];
    }
}

// ==================================================================================
// Causal flash attention (unchanged): dbuf K and V, both staged by pure DMA
// (V from V^T buffer). One __syncthreads() per tile. Complementary-qt pairing.
// ==================================================================================
#define CEXP 0.12751744f  /* (1/sqrt(128)) * log2(e) */

__global__ __launch_bounds__(256, 2) void attn_kernel(const u16* __restrict__ q,
                                                      const u16* __restrict__ k,
                                                      const u16* __restrict__ vt,
                                                      u16* __restrict__ ao) {
  __shared__ __align__(16) u16 smem[32768];  // 64 KB
  u16* kTl = smem;
  u16* vTl = smem + 16384;

  const int qt   = blockIdx.z ? (int)blockIdx.x : (int)(gridDim.x - 1 - blockIdx.x);
  const int head = blockIdx.y;
  const int b    = blockIdx.z;
  const int t = threadIdx.x;
  const int lane = t & 63;
  const int w = t >> 6;
  const int l31 = lane & 31;
  const int hi = lane >> 5;
  const int kxor = (lane & 7) << 3;
  const int qrow0 = qt * 128 + w * 32;
  const size_t bS = (size_t)b * S_;
  const size_t vhead = (size_t)(b * 16 + head) * 128 * S_;

  bf16x8 qf[8];
  {
    const u16* qrow = q + (bS + qrow0 + l31) * DIM_ + head * HD_;
#pragma unroll
    for (int st = 0; st < 8; ++st)
      qf[st] = *(const bf16x8*)(qrow + st * 16 + hi * 8);
  }

  f32x16 accO[4];
#pragma unroll
  for (int db = 0; db < 4; ++db)
#pragma unroll
    for (int rr = 0; rr < 16; ++rr) accO[db][rr] = 0.f;
  float m = -1e30f, l = 0.f;

  const int tmax_w = 2 * qt + (w >> 1);
  const int ttend = 2 * qt + 1;

  auto stageK = [&](int buf, int tt) {
#pragma unroll
    for (int p = 0; p < 4; ++p) {
      const int cid = p * 256 + w * 64 + lane;
      const int kr = cid >> 4;
      const int cg = (cid & 15) ^ (kr & 7);
      gload16(k + (bS + tt * 64 + kr) * DIM_ + head * HD_ + cg * 8,
              kTl + buf * 8192 + (p * 256 + w * 64) * 8);
    }
  };
  auto stageV = [&](int buf, int tt) {
#pragma unroll
    for (int p = 0; p < 4; ++p) {
      const int cid = p * 256 + w * 64 + lane;
      const int d = cid >> 3;
      const int cg = (cid & 7) ^ (d & 7);
      gload16(vt + vhead + (size_t)d * S_ + tt * 64 + cg * 8,
              vTl + buf * 8192 + (p * 256 + w * 64) * 8);
    }
  };

  stageK(0, 0);
  stageV(0, 0);
  __syncthreads();

  for (int tt = 0; tt <= ttend; ++tt) {
    const int cur = tt & 1;
    const int alt = cur ^ 1;

    if (tt + 1 <= ttend) {
      stageK(alt, tt + 1);
      stageV(alt, tt + 1);
    }

    if (tt <= tmax_w) {
      const u16* kB = kTl + cur * 8192;
      const u16* vB = vTl + cur * 8192;
      f32x16 sA, sB;
#pragma unroll
      for (int rr = 0; rr < 16; ++rr) { sA[rr] = 0.f; sB[rr] = 0.f; }
      __builtin_amdgcn_s_setprio(1);
#pragma unroll
      for (int st = 0; st < 8; ++st) {
        const int dc = st * 16 + hi * 8;
        bf16x8 k0 = *(const bf16x8*)(kB + l31 * 128 + (dc ^ kxor));
        bf16x8 k1 = *(const bf16x8*)(kB + (32 + l31) * 128 + (dc ^ kxor));
        sA = __builtin_amdgcn_mfma_f32_32x32x16_bf16(k0, qf[st], sA, 0, 0, 0);
        sB = __builtin_amdgcn_mfma_f32_32x32x16_bf16(k1, qf[st], sB, 0, 0, 0);
      }
      __builtin_amdgcn_s_setprio(0);

      const int qg = qrow0 + l31;
      if (tt * 64 + 63 > qrow0) {
        const int kb = tt * 64 + 4 * hi;
#pragma unroll
        for (int rr = 0; rr < 16; ++rr) {
          const int kg = kb + (rr & 3) + 8 * (rr >> 2);
          sA[rr] = (kg <= qg) ? sA[rr] : -1e30f;
          sB[rr] = (kg + 32 <= qg) ? sB[rr] : -1e30f;
        }
      }

      float mx[8];
#pragma unroll
      for (int i = 0; i < 8; ++i)
        mx[i] = fmaxf(fmaxf(sA[i], sA[i + 8]), fmaxf(sB[i], sB[i + 8]));
#pragma unroll
      for (int i = 0; i < 4; ++i) mx[i] = fmaxf(mx[i], mx[i + 4]);
      float pm = fmaxf(fmaxf(mx[0], mx[1]), fmaxf(mx[2], mx[3]));
      pm = fmaxf(pm, __shfl_xor(pm, 32));
      const float mN = fmaxf(m, pm);
      if (!__all(pm - m <= 90.5f)) {  // T13 defer-max
        const float osc = exp2f((m - mN) * CEXP);
        l *= osc;
#pragma unroll
        for (int db = 0; db < 4; ++db)
#pragma unroll
          for (int rr = 0; rr < 16; ++rr) accO[db][rr] *= osc;
        m = mN;
      }
      const float mc = m * CEXP;
      float lsv[4] = {0.f, 0.f, 0.f, 0.f};
#pragma unroll
      for (int rr = 0; rr < 16; ++rr) {
        const float pa = exp2f(__builtin_fmaf(sA[rr], CEXP, -mc));
        const float pb = exp2f(__builtin_fmaf(sB[rr], CEXP, -mc));
        sA[rr] = pa; sB[rr] = pb;
        lsv[rr & 3] += pa + pb;
      }
      float ls = (lsv[0] + lsv[1]) + (lsv[2] + lsv[3]);
      ls += __shfl_xor(ls, 32);
      l += ls;

#define PV_STEP(ARR, R0, ST2)                                                      \
      {                                                                            \
        u32 a0 = cvtpk(ARR[(R0) + 0], ARR[(R0) + 1]);                              \
        u32 a1 = cvtpk(ARR[(R0) + 2], ARR[(R0) + 3]);                              \
        u32 b0 = cvtpk(ARR[(R0) + 4], ARR[(R0) + 5]);                              \
        u32 b1 = cvtpk(ARR[(R0) + 6], ARR[(R0) + 7]);                              \
        asm("v_permlane32_swap_b32 %0, %1" : "+v"(a0), "+v"(b0));                  \
        asm("v_permlane32_swap_b32 %0, %1" : "+v"(a1), "+v"(b1));                  \
        union { u32 uu[4]; bf16x8 v8; } pf;                                        \
        pf.uu[0] = a0; pf.uu[1] = a1; pf.uu[2] = b0; pf.uu[3] = b1;                \
        const int ko = (ST2) * 16 + hi * 8;                                        \
        __builtin_amdgcn_s_setprio(1);                                             \
        _Pragma("unroll")                                                          \
        for (int db = 0; db < 4; ++db) {                                           \
          const int dr = db * 32 + l31;                                            \
          bf16x8 vf = *(const bf16x8*)(vB + dr * 64 + (ko ^ kxor));                \
          accO[db] =                                                               \
              __builtin_amdgcn_mfma_f32_32x32x16_bf16(vf, pf.v8, accO[db], 0, 0, 0); \
        }                                                                          \
        __builtin_amdgcn_s_setprio(0);                                             \
      }
      PV_STEP(sA, 0, 0)
      PV_STEP(sA, 8, 1)
      PV_STEP(sB, 0, 2)
      PV_STEP(sB, 8, 3)
#undef PV_STEP
    }

    __syncthreads();  // vmcnt(0)+lgkmcnt(0)+barrier: K/V DMA for t+1 landed
  }

  // ---- epilogue: normalize, transpose O^T->O through LDS, coalesced store ----
  const float linv = 1.0f / l;
  u16* oT = smem + w * 4352;
#pragma unroll
  for (int db = 0; db < 4; ++db)
#pragma unroll
    for (int q4 = 0; q4 < 4; ++q4) {
      const int dbase = db * 32 + q4 * 8 + hi * 4;
      const u32 lo = cvtpk(accO[db][q4 * 4 + 0] * linv, accO[db][q4 * 4 + 1] * linv);
      const u32 hiw = cvtpk(accO[db][q4 * 4 + 2] * linv, accO[db][q4 * 4 + 3] * linv);
      *(u32*)(oT + l31 * 136 + dbase) = lo;
      *(u32*)(oT + l31 * 136 + dbase + 2) = hiw;
    }
  __syncthreads();
#pragma unroll
  for (int i = 0; i < 8; ++i) {
    const int cid = i * 64 + lane;
    const int qloc = cid >> 4;
    const int c = cid & 15;
    const bf16x8 val = *(const bf16x8*)(oT + qloc * 136 + c * 8);
    *(bf16x8*)(ao + (bS + qrow0 + qloc) * DIM_ + head * HD_ + c * 8) = val;
  }
}

// ---------- launch ----------
extern "C" void kernel_launch(void* const* d_in, const int* in_sizes, int n_in,
                              void* d_out, int out_size, void* d_ws, size_t ws_size,
                              hipStream_t stream) {
  const float* x  = (const float*)d_in[0];
  const float* wq = (const float*)d_in[2];
  const float* wk = (const float*)d_in[3];
  const float* wv = (const float*)d_in[4];
  const float* wo = (const float*)d_in[5];

  char* ws = (char*)d_ws;
  size_t off = 0;
  auto carve = [&](size_t bytes) { char* p = ws + off; off += bytes; return p; };
  u16* xb   = (u16*)carve((size_t)M_ * DIM_ * 2);
  u16* wqb  = (u16*)carve((size_t)DIM_ * DIM_ * 2);
  u16* wkb  = (u16*)carve((size_t)DIM_ * DIM_ * 2);
  u16* wvb  = (u16*)carve((size_t)DIM_ * DIM_ * 2);
  u16* wob  = (u16*)carve((size_t)DIM_ * DIM_ * 2);
  u16* qb   = (u16*)carve((size_t)M_ * DIM_ * 2);
  u16* kb   = (u16*)carve((size_t)M_ * DIM_ * 2);
  u16* vtb  = (u16*)carve((size_t)M_ * DIM_ * 2);  // V^T [b][h][d][s]
  u16* aob  = (u16*)carve((size_t)M_ * DIM_ * 2);
  float* cosT = (float*)carve((size_t)64 * S_ * 4);
  float* sinT = (float*)carve((size_t)64 * S_ * 4);
  if (off > ws_size) return;

  dim3 gc(1024, 6);
  convert6_kernel<<<gc, 256, 0, stream>>>(x, wq, wk, wv, wo, xb, wqb, wkb, wvb, wob,
                                          cosT, sinT);

  gemm_qkv4_kernel<<<768, 256, 0, stream>>>(xb, wqb, wkb, wvb, qb, kb, vtb, cosT, sinT);

  dim3 ga(16, H_, B_);
  attn_kernel<<<ga, 256, 0, stream>>>(qb, kb, vtb, aob);

  gemm_out3_kernel<<<512, 256, 0, stream>>>(aob, wob, (float*)d_out);
}

// Round 17
// 241.456 us; speedup vs baseline: 1.7758x; 1.0104x over previous
//
#include <hip/hip_runtime.h>
#include <cstdint>

typedef unsigned short u16;
typedef uint32_t u32;
typedef __attribute__((ext_vector_type(8))) short bf16x8;
typedef __attribute__((ext_vector_type(4))) float f32x4;
typedef __attribute__((ext_vector_type(16))) float f32x16;

#define DIM_ 2048
#define S_   2048
#define B_   2
#define H_   16
#define HD_  128
#define M_   (B_ * S_)  // 4096

// ---------- scalar bf16 helpers (RNE) ----------
__device__ __forceinline__ u16 f2b(float f) {
  union { float f; uint32_t u; } v; v.f = f;
  uint32_t u = v.u;
  return (u16)((u + 0x7FFFu + ((u >> 16) & 1u)) >> 16);
}
__device__ __forceinline__ float b2f(u16 h) {
  union { uint32_t u; float f; } v; v.u = ((uint32_t)h) << 16;
  return v.f;
}

__device__ __forceinline__ u32 cvtpk(float lo, float hi) {
  u32 r;
  asm("v_cvt_pk_bf16_f32 %0, %1, %2" : "=v"(r) : "v"(lo), "v"(hi));
  return r;
}

// ---------- global -> LDS async copy (16B per lane, wave-uniform LDS base) ----------
typedef __attribute__((address_space(3))) u16 lds_u16_t;
typedef __attribute__((address_space(1))) const u16 glob_u16_t;

__device__ __forceinline__ void gload16(const u16* g, u16* l) {
  __builtin_amdgcn_global_load_lds((glob_u16_t*)g, (lds_u16_t*)l, 16, 0, 0);
}
#define GLD0(SRC, DST) \
  __builtin_amdgcn_global_load_lds((glob_u16_t*)(SRC), (lds_u16_t*)(DST), 16, 0, 0)

// ---------- fp32 -> bf16 convert (5 buffers) + RoPE table gen, one launch ----------
__global__ void convert6_kernel(const float* __restrict__ x, const float* __restrict__ wq,
                                const float* __restrict__ wk, const float* __restrict__ wv,
                                const float* __restrict__ wo, u16* __restrict__ xb,
                                u16* __restrict__ wqb, u16* __restrict__ wkb,
                                u16* __restrict__ wvb, u16* __restrict__ wob,
                                float* __restrict__ cosT, float* __restrict__ sinT) {
  if (blockIdx.y == 5) {
    // RoPE tables, TRANSPOSED [64 d][2048 s] fp32
    int idx = blockIdx.x * blockDim.x + threadIdx.x;
    if (idx >= 64 * S_) return;
    int d = idx >> 11;
    int s = idx & (S_ - 1);
    float inv = powf(10000.0f, -(float)d * (1.0f / 64.0f));
    float ang = (float)s * inv;
    cosT[idx] = cosf(ang);
    sinT[idx] = sinf(ang);
    return;
  }
  const float* src;
  u16* dst;
  int n;
  switch (blockIdx.y) {
    case 0: src = x;  dst = xb;  n = M_ * DIM_;   break;
    case 1: src = wq; dst = wqb; n = DIM_ * DIM_; break;
    case 2: src = wk; dst = wkb; n = DIM_ * DIM_; break;
    case 3: src = wv; dst = wvb; n = DIM_ * DIM_; break;
    default: src = wo; dst = wob; n = DIM_ * DIM_; break;
  }
  int i = (blockIdx.x * blockDim.x + threadIdx.x) * 4;
  const int stride = gridDim.x * blockDim.x * 4;
  for (; i < n; i += stride) {
    float4 v = *reinterpret_cast<const float4*>(src + i);
    uint64_t p = (uint64_t)f2b(v.x) | ((uint64_t)f2b(v.y) << 16) |
                 ((uint64_t)f2b(v.z) << 32) | ((uint64_t)f2b(v.w) << 48);
    *reinterpret_cast<uint64_t*>(dst + i) = p;
  }
}

// ==================================================================================
// GEMM v3 (QKV, R14 best-measured: 119.7 us, MfmaUtil 37.5, 3 blocks/CU):
// m97-style single-buffered 2-barrier loop sized for co-residency.
// BM=256 BN=128 BK=64; 512 thr = 8 waves (4M x 2N), wave tile 64x64 (acc 4x4 = 64
// VGPR -> no spill at high occupancy). 48 KB LDS -> 3 blocks/CU; 768 blocks = 3
// exact rounds, all co-resident (vmcnt(0) barrier drain hidden by other blocks).
// Chunk-XOR swizzle (slot = chunk ^ row&7), inverse-swizzled global src (rule 21).
// RoPE fused for z<2 (B-perm keeps (d,d+64) in-lane); z==2 writes V^T via split
// LDS bounce ([128 d][136 s], 2 s-half passes).
// ==================================================================================
#define NT_ 32  // 2048 / 64

__global__ __launch_bounds__(512, 4) void gemm_qkv3_kernel(
    const u16* __restrict__ xb, const u16* __restrict__ wqb, const u16* __restrict__ wkb,
    const u16* __restrict__ wvb, u16* __restrict__ qb, u16* __restrict__ kb,
    u16* __restrict__ vtb, const float* __restrict__ cosT, const float* __restrict__ sinT) {
  __shared__ __align__(16) u16 lds[24576];  // 48 KB: A [256][64] @0, B [128][64] @16384

  // XCD swizzle (768 % 8 == 0) + A-panel grouping: logical = mt*48 + z*16 + nt
  const int bid = blockIdx.x;
  const int logical = (bid & 7) * 96 + (bid >> 3);
  const int mt = logical / 48;
  const int rem = logical % 48;
  const int z = rem >> 4;
  const int nt = rem & 15;
  const u16* Wm = (z == 0) ? wqb : (z == 1) ? wkb : wvb;
  u16* out = (z == 0) ? qb : (z == 1) ? kb : vtb;

  const int tid = threadIdx.x;
  const int lane = tid & 63;
  const int w = tid >> 6;
  const int wm = w >> 1, wn = w & 1;   // 4M x 2N
  const int l15 = lane & 15, lg = lane >> 4;

  const u16* sA = xb + (size_t)(mt * 256) * DIM_;
  const u16* sB = Wm + (size_t)(nt * 128) * DIM_;

  // stage source voffset: row = tid>>3 (+64*sweep), chunk = (tid&7) ^ (row&7)
  const int r8 = tid >> 3;
  const int goffs = r8 * DIM_ + (((tid & 7) ^ (r8 & 7)) * 8);

  // LDS read bases (chunk ^= row&7; row%16 == l15 so row&7 == l15&7)
  const int x7 = l15 & 7;
  const int lrk0 = ((lg) ^ x7) * 8;
  const int lrk1 = ((4 | lg) ^ x7) * 8;
  const u16* pA0 = lds + (wm * 64 + l15) * 64 + lrk0;
  const u16* pA1 = lds + (wm * 64 + l15) * 64 + lrk1;
  const u16* pB0 = lds + 16384 + (wn * 32 + l15) * 64 + lrk0;
  const u16* pB1 = lds + 16384 + (wn * 32 + l15) * 64 + lrk1;

  f32x4 acc[4][4];
#pragma unroll
  for (int i = 0; i < 4; ++i)
#pragma unroll
    for (int j = 0; j < 4; ++j) acc[i][j] = (f32x4){0.f, 0.f, 0.f, 0.f};

  bf16x8 a[4], b[4];

  for (int t = 0; t < NT_; ++t) {
    __syncthreads();  // previous tile's frag reads complete before overwrite
#pragma unroll
    for (int s = 0; s < 4; ++s)
      GLD0(sA + goffs + s * (64 * DIM_), lds + s * 4096 + w * 512);
#pragma unroll
    for (int s = 0; s < 2; ++s)
      GLD0(sB + goffs + s * (64 * DIM_), lds + 16384 + s * 4096 + w * 512);
    sA += 64; sB += 64;
    __syncthreads();  // vmcnt(0) drain -> tile ready (hidden by co-resident blocks)

    // ks0: B-perm rows (ni&1)*16 + (ni>>1)*64
#pragma unroll
    for (int mi = 0; mi < 4; ++mi) a[mi] = *(const bf16x8*)(pA0 + mi * 1024);
#pragma unroll
    for (int ni = 0; ni < 4; ++ni)
      b[ni] = *(const bf16x8*)(pB0 + (ni & 1) * 1024 + (ni >> 1) * 4096);
    __builtin_amdgcn_s_setprio(1);
#pragma unroll
    for (int mi = 0; mi < 4; ++mi)
#pragma unroll
      for (int ni = 0; ni < 4; ++ni)
        acc[mi][ni] = __builtin_amdgcn_mfma_f32_16x16x32_bf16(a[mi], b[ni], acc[mi][ni], 0, 0, 0);
    __builtin_amdgcn_s_setprio(0);
    // ks1
#pragma unroll
    for (int mi = 0; mi < 4; ++mi) a[mi] = *(const bf16x8*)(pA1 + mi * 1024);
#pragma unroll
    for (int ni = 0; ni < 4; ++ni)
      b[ni] = *(const bf16x8*)(pB1 + (ni & 1) * 1024 + (ni >> 1) * 4096);
    __builtin_amdgcn_s_setprio(1);
#pragma unroll
    for (int mi = 0; mi < 4; ++mi)
#pragma unroll
      for (int ni = 0; ni < 4; ++ni)
        acc[mi][ni] = __builtin_amdgcn_mfma_f32_16x16x32_bf16(a[mi], b[ni], acc[mi][ni], 0, 0, 0);
    __builtin_amdgcn_s_setprio(0);
  }

  if (z < 2) {
    // ---- fused RoPE epilogue: pair (d, d+64) = acc[mi][ni] / acc[mi][ni+2] ----
#pragma unroll
    for (int mi = 0; mi < 4; ++mi) {
      const int row = mt * 256 + wm * 64 + mi * 16 + lg * 4;
      const int s = row & (S_ - 1);
#pragma unroll
      for (int ni = 0; ni < 2; ++ni) {
        const int d = wn * 32 + ni * 16 + l15;  // < 64
        const float4 c4 = *(const float4*)(cosT + d * S_ + s);
        const float4 s4 = *(const float4*)(sinT + d * S_ + s);
        const float cc[4]  = {c4.x, c4.y, c4.z, c4.w};
        const float ssn[4] = {s4.x, s4.y, s4.z, s4.w};
        u16* p = out + (size_t)row * DIM_ + nt * 128 + d;
#pragma unroll
        for (int r = 0; r < 4; ++r) {
          const float t1 = acc[mi][ni][r];
          const float t2 = acc[mi][ni + 2][r];
          p[(size_t)r * DIM_]      = f2b(t1 * cc[r] - t2 * ssn[r]);
          p[(size_t)r * DIM_ + 64] = f2b(t2 * cc[r] + t1 * ssn[r]);
        }
      }
    }
  } else {
    // ---- V^T epilogue: split LDS bounce [128 d][136 s] x 2 passes (s-halves) ----
    const int bq = mt >> 3;
    const int sbase = (mt * 256) & (S_ - 1);
#pragma unroll
    for (int shalf = 0; shalf < 2; ++shalf) {
      __syncthreads();  // K-loop reads / previous pass streams complete
      if ((wm >> 1) == shalf) {
#pragma unroll
        for (int mi = 0; mi < 4; ++mi) {
          const int sl = (wm & 1) * 64 + mi * 16 + lg * 4;  // 0..127
#pragma unroll
          for (int ni = 0; ni < 4; ++ni) {
            const int d = wn * 32 + (ni & 1) * 16 + (ni >> 1) * 64 + l15;  // 0..127
            const u32 lo  = cvtpk(acc[mi][ni][0], acc[mi][ni][1]);
            const u32 hi2 = cvtpk(acc[mi][ni][2], acc[mi][ni][3]);
            const uint64_t pk = (uint64_t)lo | ((uint64_t)hi2 << 32);
            *(uint64_t*)(lds + d * 136 + sl) = pk;
          }
        }
      }
      __syncthreads();
      // stream: each wave covers 4 cols per iter (lane>>4), lanes&15 cover 128 s
#pragma unroll
      for (int it = 0; it < 4; ++it) {
        const int d = it * 32 + w * 4 + (lane >> 4);  // 0..127
        const bf16x8 val = *(const bf16x8*)(lds + d * 136 + (lane & 15) * 8);
        *(bf16x8*)(out + ((size_t)(bq * 16 + nt) * 128 + d) * S_ + sbase + shalf * 128 +
                   (lane & 15) * 8) = val;
      }
    }
  }
}

// ---------------- O-projection: BM=128 BN=128, 256 thr / 4 waves, 32 KB LDS ----------------
__global__ __launch_bounds__(256, 4) void gemm_out3_kernel(const u16* __restrict__ A,
                                                           const u16* __restrict__ W,
                                                           float* __restrict__ Cf) {
  __shared__ __align__(16) u16 lds[16384];  // 32 KB: A [128][64] @0, B [128][64] @8192
  const int bid = blockIdx.x;  // 512 blocks, all resident
  const int logical = (bid & 7) * 64 + (bid >> 3);
  const int mt = logical >> 4;  // 0..31
  const int nt = logical & 15;

  const int tid = threadIdx.x;
  const int lane = tid & 63;
  const int w = tid >> 6;
  const int wm = w >> 1, wn = w & 1;
  const int l15 = lane & 15, lg = lane >> 4;

  const u16* sA = A + (size_t)(mt * 128) * DIM_;
  const u16* sB = W + (size_t)(nt * 128) * DIM_;

  const int r8 = tid >> 3;  // 0..31
  const int goffs = r8 * DIM_ + (((tid & 7) ^ (r8 & 7)) * 8);

  const int x7 = l15 & 7;
  const int lrk0 = ((lg) ^ x7) * 8;
  const int lrk1 = ((4 | lg) ^ x7) * 8;
  const u16* pA0 = lds + (wm * 64 + l15) * 64 + lrk0;
  const u16* pA1 = lds + (wm * 64 + l15) * 64 + lrk1;
  const u16* pB0 = lds + 8192 + (wn * 64 + l15) * 64 + lrk0;
  const u16* pB1 = lds + 8192 + (wn * 64 + l15) * 64 + lrk1;

  f32x4 acc[4][4];
#pragma unroll
  for (int i = 0; i < 4; ++i)
#pragma unroll
    for (int j = 0; j < 4; ++j) acc[i][j] = (f32x4){0.f, 0.f, 0.f, 0.f};

  bf16x8 a[4], b[4];

  for (int t = 0; t < NT_; ++t) {
    __syncthreads();
#pragma unroll
    for (int s = 0; s < 4; ++s)
      GLD0(sA + goffs + s * (32 * DIM_), lds + s * 2048 + w * 512);
#pragma unroll
    for (int s = 0; s < 4; ++s)
      GLD0(sB + goffs + s * (32 * DIM_), lds + 8192 + s * 2048 + w * 512);
    sA += 64; sB += 64;
    __syncthreads();

#pragma unroll
    for (int mi = 0; mi < 4; ++mi) a[mi] = *(const bf16x8*)(pA0 + mi * 1024);
#pragma unroll
    for (int ni = 0; ni < 4; ++ni) b[ni] = *(const bf16x8*)(pB0 + ni * 1024);
    __builtin_amdgcn_s_setprio(1);
#pragma unroll
    for (int mi = 0; mi < 4; ++mi)
#pragma unroll
      for (int ni = 0; ni < 4; ++ni)
        acc[mi][ni] = __builtin_amdgcn_mfma_f32_16x16x32_bf16(a[mi], b[ni], acc[mi][ni], 0, 0, 0);
    __builtin_amdgcn_s_setprio(0);
#pragma unroll
    for (int mi = 0; mi < 4; ++mi) a[mi] = *(const bf16x8*)(pA1 + mi * 1024);
#pragma unroll
    for (int ni = 0; ni < 4; ++ni) b[ni] = *(const bf16x8*)(pB1 + ni * 1024);
    __builtin_amdgcn_s_setprio(1);
#pragma unroll
    for (int mi = 0; mi < 4; ++mi)
#pragma unroll
      for (int ni = 0; ni < 4; ++ni)
        acc[mi][ni] = __builtin_amdgcn_mfma_f32_16x16x32_bf16(a[mi], b[ni], acc[mi][ni], 0, 0, 0);
    __builtin_amdgcn_s_setprio(0);
  }

#pragma unroll
  for (int mi = 0; mi < 4; ++mi)
#pragma unroll
    for (int ni = 0; ni < 4; ++ni) {
      const int row = mt * 128 + wm * 64 + mi * 16 + lg * 4;
      const int col = nt * 128 + wn * 64 + ni * 16 + l15;
#pragma unroll
      for (int r = 0; r < 4; ++r)
        Cf[(size_t)(row + r) * DIM_ + col] = acc[mi][ni][r];
    }
}

// ==================================================================================
// Causal flash attention (unchanged): dbuf K and V, both staged by pure DMA
// (V from V^T buffer). One __syncthreads() per tile. Complementary-qt pairing.
// ==================================================================================
#define CEXP 0.12751744f  /* (1/sqrt(128)) * log2(e) */

__global__ __launch_bounds__(256, 2) void attn_kernel(const u16* __restrict__ q,
                                                      const u16* __restrict__ k,
                                                      const u16* __restrict__ vt,
                                                      u16* __restrict__ ao) {
  __shared__ __align__(16) u16 smem[32768];  // 64 KB
  u16* kTl = smem;
  u16* vTl = smem + 16384;

  const int qt   = blockIdx.z ? (int)blockIdx.x : (int)(gridDim.x - 1 - blockIdx.x);
  const int head = blockIdx.y;
  const int b    = blockIdx.z;
  const int t = threadIdx.x;
  const int lane = t & 63;
  const int w = t >> 6;
  const int l31 = lane & 31;
  const int hi = lane >> 5;
  const int kxor = (lane & 7) << 3;
  const int qrow0 = qt * 128 + w * 32;
  const size_t bS = (size_t)b * S_;
  const size_t vhead = (size_t)(b * 16 + head) * 128 * S_;

  bf16x8 qf[8];
  {
    const u16* qrow = q + (bS + qrow0 + l31) * DIM_ + head * HD_;
#pragma unroll
    for (int st = 0; st < 8; ++st)
      qf[st] = *(const bf16x8*)(qrow + st * 16 + hi * 8);
  }

  f32x16 accO[4];
#pragma unroll
  for (int db = 0; db < 4; ++db)
#pragma unroll
    for (int rr = 0; rr < 16; ++rr) accO[db][rr] = 0.f;
  float m = -1e30f, l = 0.f;

  const int tmax_w = 2 * qt + (w >> 1);
  const int ttend = 2 * qt + 1;

  auto stageK = [&](int buf, int tt) {
#pragma unroll
    for (int p = 0; p < 4; ++p) {
      const int cid = p * 256 + w * 64 + lane;
      const int kr = cid >> 4;
      const int cg = (cid & 15) ^ (kr & 7);
      gload16(k + (bS + tt * 64 + kr) * DIM_ + head * HD_ + cg * 8,
              kTl + buf * 8192 + (p * 256 + w * 64) * 8);
    }
  };
  auto stageV = [&](int buf, int tt) {
#pragma unroll
    for (int p = 0; p < 4; ++p) {
      const int cid = p * 256 + w * 64 + lane;
      const int d = cid >> 3;
      const int cg = (cid & 7) ^ (d & 7);
      gload16(vt + vhead + (size_t)d * S_ + tt * 64 + cg * 8,
              vTl + buf * 8192 + (p * 256 + w * 64) * 8);
    }
  };

  stageK(0, 0);
  stageV(0, 0);
  __syncthreads();

  for (int tt = 0; tt <= ttend; ++tt) {
    const int cur = tt & 1;
    const int alt = cur ^ 1;

    if (tt + 1 <= ttend) {
      stageK(alt, tt + 1);
      stageV(alt, tt + 1);
    }

    if (tt <= tmax_w) {
      const u16* kB = kTl + cur * 8192;
      const u16* vB = vTl + cur * 8192;
      f32x16 sA, sB;
#pragma unroll
      for (int rr = 0; rr < 16; ++rr) { sA[rr] = 0.f; sB[rr] = 0.f; }
      __builtin_amdgcn_s_setprio(1);
#pragma unroll
      for (int st = 0; st < 8; ++st) {
        const int dc = st * 16 + hi * 8;
        bf16x8 k0 = *(const bf16x8*)(kB + l31 * 128 + (dc ^ kxor));
        bf16x8 k1 = *(const bf16x8*)(kB + (32 + l31) * 128 + (dc ^ kxor));
        sA = __builtin_amdgcn_mfma_f32_32x32x16_bf16(k0, qf[st], sA, 0, 0, 0);
        sB = __builtin_amdgcn_mfma_f32_32x32x16_bf16(k1, qf[st], sB, 0, 0, 0);
      }
      __builtin_amdgcn_s_setprio(0);

      const int qg = qrow0 + l31;
      if (tt * 64 + 63 > qrow0) {
        const int kb = tt * 64 + 4 * hi;
#pragma unroll
        for (int rr = 0; rr < 16; ++rr) {
          const int kg = kb + (rr & 3) + 8 * (rr >> 2);
          sA[rr] = (kg <= qg) ? sA[rr] : -1e30f;
          sB[rr] = (kg + 32 <= qg) ? sB[rr] : -1e30f;
        }
      }

      float mx[8];
#pragma unroll
      for (int i = 0; i < 8; ++i)
        mx[i] = fmaxf(fmaxf(sA[i], sA[i + 8]), fmaxf(sB[i], sB[i + 8]));
#pragma unroll
      for (int i = 0; i < 4; ++i) mx[i] = fmaxf(mx[i], mx[i + 4]);
      float pm = fmaxf(fmaxf(mx[0], mx[1]), fmaxf(mx[2], mx[3]));
      pm = fmaxf(pm, __shfl_xor(pm, 32));
      const float mN = fmaxf(m, pm);
      if (!__all(pm - m <= 90.5f)) {  // T13 defer-max
        const float osc = exp2f((m - mN) * CEXP);
        l *= osc;
#pragma unroll
        for (int db = 0; db < 4; ++db)
#pragma unroll
          for (int rr = 0; rr < 16; ++rr) accO[db][rr] *= osc;
        m = mN;
      }
      const float mc = m * CEXP;
      float lsv[4] = {0.f, 0.f, 0.f, 0.f};
#pragma unroll
      for (int rr = 0; rr < 16; ++rr) {
        const float pa = exp2f(__builtin_fmaf(sA[rr], CEXP, -mc));
        const float pb = exp2f(__builtin_fmaf(sB[rr], CEXP, -mc));
        sA[rr] = pa; sB[rr] = pb;
        lsv[rr & 3] += pa + pb;
      }
      float ls = (lsv[0] + lsv[1]) + (lsv[2] + lsv[3]);
      ls += __shfl_xor(ls, 32);
      l += ls;

#define PV_STEP(ARR, R0, ST2)                                                      \
      {                                                                            \
        u32 a0 = cvtpk(ARR[(R0) + 0], ARR[(R0) + 1]);                              \
        u32 a1 = cvtpk(ARR[(R0) + 2], ARR[(R0) + 3]);                              \
        u32 b0 = cvtpk(ARR[(R0) + 4], ARR[(R0) + 5]);                              \
        u32 b1 = cvtpk(ARR[(R0) + 6], ARR[(R0) + 7]);                              \
        asm("v_permlane32_swap_b32 %0, %1" : "+v"(a0), "+v"(b0));                  \
        asm("v_permlane32_swap_b32 %0, %1" : "+v"(a1), "+v"(b1));                  \
        union { u32 uu[4]; bf16x8 v8; } pf;                                        \
        pf.uu[0] = a0; pf.uu[1] = a1; pf.uu[2] = b0; pf.uu[3] = b1;                \
        const int ko = (ST2) * 16 + hi * 8;                                        \
        __builtin_amdgcn_s_setprio(1);                                             \
        _Pragma("unroll")                                                          \
        for (int db = 0; db < 4; ++db) {                                           \
          const int dr = db * 32 + l31;                                            \
          bf16x8 vf = *(const bf16x8*)(vB + dr * 64 + (ko ^ kxor));                \
          accO[db] =                                                               \
              __builtin_amdgcn_mfma_f32_32x32x16_bf16(vf, pf.v8, accO[db], 0, 0, 0); \
        }                                                                          \
        __builtin_amdgcn_s_setprio(0);                                             \
      }
      PV_STEP(sA, 0, 0)
      PV_STEP(sA, 8, 1)
      PV_STEP(sB, 0, 2)
      PV_STEP(sB, 8, 3)
#undef PV_STEP
    }

    __syncthreads();  // vmcnt(0)+lgkmcnt(0)+barrier: K/V DMA for t+1 landed
  }

  // ---- epilogue: normalize, transpose O^T->O through LDS, coalesced store ----
  const float linv = 1.0f / l;
  u16* oT = smem + w * 4352;
#pragma unroll
  for (int db = 0; db < 4; ++db)
#pragma unroll
    for (int q4 = 0; q4 < 4; ++q4) {
      const int dbase = db * 32 + q4 * 8 + hi * 4;
      const u32 lo = cvtpk(accO[db][q4 * 4 + 0] * linv, accO[db][q4 * 4 + 1] * linv);
      const u32 hiw = cvtpk(accO[db][q4 * 4 + 2] * linv, accO[db][q4 * 4 + 3] * linv);
      *(u32*)(oT + l31 * 136 + dbase) = lo;
      *(u32*)(oT + l31 * 136 + dbase + 2) = hiw;
    }
  __syncthreads();
#pragma unroll
  for (int i = 0; i < 8; ++i) {
    const int cid = i * 64 + lane;
    const int qloc = cid >> 4;
    const int c = cid & 15;
    const bf16x8 val = *(const bf16x8*)(oT + qloc * 136 + c * 8);
    *(bf16x8*)(ao + (bS + qrow0 + qloc) * DIM_ + head * HD_ + c * 8) = val;
  }
}

// ---------- launch ----------
extern "C" void kernel_launch(void* const* d_in, const int* in_sizes, int n_in,
                              void* d_out, int out_size, void* d_ws, size_t ws_size,
                              hipStream_t stream) {
  const float* x  = (const float*)d_in[0];
  const float* wq = (const float*)d_in[2];
  const float* wk = (const float*)d_in[3];
  const float* wv = (const float*)d_in[4];
  const float* wo = (const float*)d_in[5];

  char* ws = (char*)d_ws;
  size_t off = 0;
  auto carve = [&](size_t bytes) { char* p = ws + off; off += bytes; return p; };
  u16* xb   = (u16*)carve((size_t)M_ * DIM_ * 2);
  u16* wqb  = (u16*)carve((size_t)DIM_ * DIM_ * 2);
  u16* wkb  = (u16*)carve((size_t)DIM_ * DIM_ * 2);
  u16* wvb  = (u16*)carve((size_t)DIM_ * DIM_ * 2);
  u16* wob  = (u16*)carve((size_t)DIM_ * DIM_ * 2);
  u16* qb   = (u16*)carve((size_t)M_ * DIM_ * 2);
  u16* kb   = (u16*)carve((size_t)M_ * DIM_ * 2);
  u16* vtb  = (u16*)carve((size_t)M_ * DIM_ * 2);  // V^T [b][h][d][s]
  u16* aob  = (u16*)carve((size_t)M_ * DIM_ * 2);
  float* cosT = (float*)carve((size_t)64 * S_ * 4);
  float* sinT = (float*)carve((size_t)64 * S_ * 4);
  if (off > ws_size) return;

  dim3 gc(1024, 6);
  convert6_kernel<<<gc, 256, 0, stream>>>(x, wq, wk, wv, wo, xb, wqb, wkb, wvb, wob,
                                          cosT, sinT);

  gemm_qkv3_kernel<<<768, 512, 0, stream>>>(xb, wqb, wkb, wvb, qb, kb, vtb, cosT, sinT);

  dim3 ga(16, H_, B_);
  attn_kernel<<<ga, 256, 0, stream>>>(qb, kb, vtb, aob);

  gemm_out3_kernel<<<512, 256, 0, stream>>>(aob, wob, (float*)d_out);
}